// Round 17
// baseline (156.263 us; speedup 1.0000x reference)
//
#include <hip/hip_runtime.h>
#include <stdint.h>

// Problem constants (fixed by the reference): P=8192, L=64, H=128.
#define PCNT 8192
#define LROW 64
#define HDIM 128
#define XSTR 136                    // x_lds k-stride (f16), 16B aligned
#define W1STR 136                   // W1^T k-stride (K=128 + 8 pad)
#define W23STR 264                  // W2^T/W3^T k-stride (K=256 + 8 pad)
#define W1_ELEMS (128 * W1STR)      // 17408
#define W23_ELEMS (128 * W23STR)    // 33792

typedef _Float16 f16;
typedef __attribute__((ext_vector_type(8))) _Float16 half8;
typedef __attribute__((ext_vector_type(2))) __fp16 fp16x2;   // builtin cvt_pkrtz type
typedef __attribute__((ext_vector_type(4))) float f32x4;

#define MFMA16(A, B, C) __builtin_amdgcn_mfma_f32_16x16x32_f16((A), (B), (C), 0, 0, 0)

__device__ __forceinline__ half8 ldh8(const f16* p) {
  return *reinterpret_cast<const half8*>(p);
}

union PkU { uint32_t u; fp16x2 h; };
union U4H8 { uint4 u; half8 h; };

// f32 pair -> packed f16 (round-toward-zero), 1 instruction
__device__ __forceinline__ uint32_t pkrtz2(float a, float b) {
  PkU r;
  r.h = __builtin_amdgcn_cvt_pkrtz(a, b);
  return r.u;
}

// 8 consecutive f32 from global -> half8 fragment (2 b128 loads + 4 cvt)
__device__ __forceinline__ half8 ld_cvt8(const float* p) {
  float4 a = *reinterpret_cast<const float4*>(p);
  float4 b = *reinterpret_cast<const float4*>(p + 4);
  U4H8 r;
  r.u.x = pkrtz2(a.x, a.y);
  r.u.y = pkrtz2(a.z, a.w);
  r.u.z = pkrtz2(b.x, b.y);
  r.u.w = pkrtz2(b.z, b.w);
  return r.h;
}

__device__ __forceinline__ uint32_t pkmax(uint32_t a, uint32_t b) {
  uint32_t d;
  asm("v_pk_max_f16 %0, %1, %2" : "=v"(d) : "v"(a), "v"(b));
  return d;
}
__device__ __forceinline__ uint32_t pkadd(uint32_t a, uint32_t b) {
  uint32_t d;
  asm("v_pk_add_f16 %0, %1, %2" : "=v"(d) : "v"(a), "v"(b));
  return d;
}
__device__ __forceinline__ uint32_t pkmul(uint32_t a, uint32_t b) {
  uint32_t d;
  asm("v_pk_mul_f16 %0, %1, %2" : "=v"(d) : "v"(a), "v"(b));
  return d;
}
__device__ __forceinline__ uint32_t pkfma(uint32_t a, uint32_t b, uint32_t c) {
  uint32_t d;
  asm("v_pk_fma_f16 %0, %1, %2, %3" : "=v"(d) : "v"(a), "v"(b), "v"(c));
  return d;
}

// ---------------------------------------------------------------------------
// Prep: ws = 3 transposed fp16 weight buffers (fused-K layout):
//   buf0 @0:                 W1^T  [c][k], k<128 real, stride 136
//   buf1 @W1_ELEMS:          W2^T  [c][k], k<256 real (Wa2|Wb2), stride 264
//   buf2 @W1_ELEMS+W23_ELEMS W3^T  same, stride 264
// ---------------------------------------------------------------------------
__global__ void prep_weights(const float* __restrict__ W1,
                             const float* __restrict__ W2,
                             const float* __restrict__ W3,
                             f16* __restrict__ wt) {
  int idx = blockIdx.x * 256 + threadIdx.x;
  if (idx >= W1_ELEMS + 2 * W23_ELEMS) return;
  float v = 0.0f;
  if (idx < W1_ELEMS) {
    int c = idx / W1STR, k = idx - c * W1STR;
    if (k < 128) v = W1[k * 128 + c];
  } else {
    int rem = idx - W1_ELEMS;
    const float* W = (rem < W23_ELEMS) ? W2 : W3;
    if (rem >= W23_ELEMS) rem -= W23_ELEMS;
    int c = rem / W23STR, k = rem - c * W23STR;
    if (k < 256) v = W[k * 128 + c];
  }
  wt[idx] = (f16)v;
}

// ---------------------------------------------------------------------------
// Fused kernel (R15 base, DS-pressure cut): transposed-D, TWO polylines per
// block concurrent (one weight-fragment load feeds both GEMMs), fused-K
// (K=256 on layers 1/2, phi fragments uniform -> rank-1 concat term), bias
// seeds acc, packed-f16 epilogue.
// R17 delta vs R15: layer-0 B-fragments are read DIRECTLY from global fp32
// with in-loop cvt_pkrtz (no staging phase, no staging barrier, no layer-0
// LDS reads) — the DS pipe is the measured bottleneck (~53 ds ops/layer/wave
// ~= the 112us wall); this removes ~15% of DS ops and one barrier. x' for
// layers 1/2 still goes through LDS (it IS the lane transpose).
// __launch_bounds__(256,4): proven spill-free regime (~100 VGPR).
// ---------------------------------------------------------------------------
__global__ __launch_bounds__(256, 4)
void fused_subgraph(const float* __restrict__ hs,
                    const int* __restrict__ lens,
                    const f16* __restrict__ wt,
                    const float* __restrict__ b1, const float* __restrict__ g1, const float* __restrict__ be1,
                    const float* __restrict__ b2, const float* __restrict__ g2, const float* __restrict__ be2,
                    const float* __restrict__ b3, const float* __restrict__ g3, const float* __restrict__ be3,
                    float* __restrict__ out) {
  __shared__ __align__(16) f16 xA[LROW * XSTR];      // x' buffer (layers 1/2)
  __shared__ __align__(16) f16 xB[LROW * XSTR];
  __shared__ __align__(16) float2 stats_s[2][LROW][4];  // [poly][row][wave]
  __shared__ __align__(16) f16 phiA[HDIM];
  __shared__ __align__(16) f16 phiB[HDIM];

  const int tid = threadIdx.x;
  const int w = tid >> 6;   // wave 0..3
  const int l = tid & 63;   // lane
  const int pA = blockIdx.x * 2;
  const int pB = pA + 1;

  int lenA = lens[pA];
  lenA = (lenA < 1) ? 1 : (lenA > LROW ? LROW : lenA);
  const int mtA = (lenA + 15) >> 4;
  int lenB = lens[pB];
  lenB = (lenB < 1) ? 1 : (lenB > LROW ? LROW : lenB);
  const int mtB = (lenB + 15) >> 4;

  const int l15 = l & 15;
  const int lg = l >> 4;                    // lane group 0..3
  const int ko = lg * 8;                    // k offset within a 32-k tile
  const int cb0 = w * 32 + lg * 4;          // lane's col base, nt=0
  const int cb1 = cb0 + 16;                 // nt=1

  const float* hpA = hs + (size_t)pA * (LROW * HDIM);
  const float* hpB = hs + (size_t)pB * (LROW * HDIM);

  // no staging phase, no initial barrier: layer 0 reads x straight from
  // global; xA/xB first written in layer-0 epilogue, read in layer-1 GEMM
  // (separated by the layer-0 end barrier).

#pragma unroll
  for (int layer = 0; layer < 3; ++layer) {
    const float* gv  = (layer == 0) ? g1  : (layer == 1) ? g2  : g3;
    const float* bev = (layer == 0) ? be1 : (layer == 1) ? be2 : be3;
    const float* bv  = (layer == 0) ? b1  : (layer == 1) ? b2  : b3;
    const f16* wa = (layer == 0) ? wt
                   : (layer == 1) ? (wt + W1_ELEMS)
                                  : (wt + W1_ELEMS + W23_ELEMS);
    const int wstr = (layer == 0) ? W1STR : W23STR;
    const int kcN  = (layer == 0) ? 4 : 8;
    const int wrow0 = (w * 32 + l15) * wstr;
    const int wrow1 = wrow0 + 16 * wstr;

    // ---- GEMM both polylines: acc = bias + (x~ @ W~)^T, K=128/256 ----
    f32x4 aA[4][2], aB[4][2];
    {
      const float4 bl0 = *reinterpret_cast<const float4*>(bv + cb0);
      const float4 bl1 = *reinterpret_cast<const float4*>(bv + cb1);
      f32x4 s0, s1;
      s0[0] = bl0.x; s0[1] = bl0.y; s0[2] = bl0.z; s0[3] = bl0.w;
      s1[0] = bl1.x; s1[1] = bl1.y; s1[2] = bl1.z; s1[3] = bl1.w;
#pragma unroll
      for (int mt = 0; mt < 4; ++mt) {
        if (mt < mtA) { aA[mt][0] = s0; aA[mt][1] = s1; }
        if (mt < mtB) { aB[mt][0] = s0; aB[mt][1] = s1; }
      }
    }
#pragma unroll
    for (int kc = 0; kc < 8; ++kc) {
      if (kc >= kcN) break;
      half8 wa0 = ldh8(&wa[wrow0 + kc * 32 + ko]);   // one load, two polylines
      half8 wa1 = ldh8(&wa[wrow1 + kc * 32 + ko]);
      if (kc < 4) {
#pragma unroll
        for (int mt = 0; mt < 4; ++mt) {
          if (mt < mtA) {
            half8 bx = (layer == 0)
                ? ld_cvt8(hpA + (mt * 16 + l15) * HDIM + kc * 32 + ko)
                : ldh8(&xA[(mt * 16 + l15) * XSTR + kc * 32 + ko]);
            aA[mt][0] = MFMA16(wa0, bx, aA[mt][0]);
            aA[mt][1] = MFMA16(wa1, bx, aA[mt][1]);
          }
        }
#pragma unroll
        for (int mt = 0; mt < 4; ++mt) {
          if (mt < mtB) {
            half8 bx = (layer == 0)
                ? ld_cvt8(hpB + (mt * 16 + l15) * HDIM + kc * 32 + ko)
                : ldh8(&xB[(mt * 16 + l15) * XSTR + kc * 32 + ko]);
            aB[mt][0] = MFMA16(wa0, bx, aB[mt][0]);
            aB[mt][1] = MFMA16(wa1, bx, aB[mt][1]);
          }
        }
      } else {
        half8 phfA = ldh8(&phiA[(kc - 4) * 32 + ko]);  // uniform -> row-const
        half8 phfB = ldh8(&phiB[(kc - 4) * 32 + ko]);
#pragma unroll
        for (int mt = 0; mt < 4; ++mt) {
          if (mt < mtA) {
            aA[mt][0] = MFMA16(wa0, phfA, aA[mt][0]);
            aA[mt][1] = MFMA16(wa1, phfA, aA[mt][1]);
          }
        }
#pragma unroll
        for (int mt = 0; mt < 4; ++mt) {
          if (mt < mtB) {
            aB[mt][0] = MFMA16(wa0, phfB, aB[mt][0]);
            aB[mt][1] = MFMA16(wa1, phfB, aB[mt][1]);
          }
        }
      }
    }

    // ---- LN stats both polylines (f32) ----
#pragma unroll
    for (int mt = 0; mt < 4; ++mt) {
      if (mt < mtA) {
        const f32x4 a0 = aA[mt][0], a1 = aA[mt][1];
        float s = ((a0[0] + a0[1]) + (a0[2] + a0[3])) + ((a1[0] + a1[1]) + (a1[2] + a1[3]));
        float q = a0[0] * a0[0];
        q = fmaf(a0[1], a0[1], q); q = fmaf(a0[2], a0[2], q); q = fmaf(a0[3], a0[3], q);
        q = fmaf(a1[0], a1[0], q); q = fmaf(a1[1], a1[1], q);
        q = fmaf(a1[2], a1[2], q); q = fmaf(a1[3], a1[3], q);
        s += __shfl_xor(s, 16); q += __shfl_xor(q, 16);
        s += __shfl_xor(s, 32); q += __shfl_xor(q, 32);
        if (l < 16) stats_s[0][mt * 16 + l15][w] = make_float2(s, q);
      }
    }
#pragma unroll
    for (int mt = 0; mt < 4; ++mt) {
      if (mt < mtB) {
        const f32x4 a0 = aB[mt][0], a1 = aB[mt][1];
        float s = ((a0[0] + a0[1]) + (a0[2] + a0[3])) + ((a1[0] + a1[1]) + (a1[2] + a1[3]));
        float q = a0[0] * a0[0];
        q = fmaf(a0[1], a0[1], q); q = fmaf(a0[2], a0[2], q); q = fmaf(a0[3], a0[3], q);
        q = fmaf(a1[0], a1[0], q); q = fmaf(a1[1], a1[1], q);
        q = fmaf(a1[2], a1[2], q); q = fmaf(a1[3], a1[3], q);
        s += __shfl_xor(s, 16); q += __shfl_xor(q, 16);
        s += __shfl_xor(s, 32); q += __shfl_xor(q, 32);
        if (l < 16) stats_s[1][mt * 16 + l15][w] = make_float2(s, q);
      }
    }
    __syncthreads();

    // ---- epilogues, packed f16 (shared g/beta packs) ----
    const float4 gg0 = *reinterpret_cast<const float4*>(gv + cb0);
    const float4 gg1 = *reinterpret_cast<const float4*>(gv + cb1);
    const float4 eb0 = *reinterpret_cast<const float4*>(bev + cb0);
    const float4 eb1 = *reinterpret_cast<const float4*>(bev + cb1);
    const uint32_t gp0 = pkrtz2(gg0.x, gg0.y), gp1 = pkrtz2(gg0.z, gg0.w);
    const uint32_t gp2 = pkrtz2(gg1.x, gg1.y), gp3 = pkrtz2(gg1.z, gg1.w);
    const uint32_t bp0 = pkrtz2(eb0.x, eb0.y), bp1 = pkrtz2(eb0.z, eb0.w);
    const uint32_t bp2 = pkrtz2(eb1.x, eb1.y), bp3 = pkrtz2(eb1.z, eb1.w);
    const uint32_t zero = 0u;

#pragma unroll
    for (int poly = 0; poly < 2; ++poly) {
      const int mtP = poly ? mtB : mtA;
      const int lenP = poly ? lenB : lenA;
      f16* xP = poly ? xB : xA;
      f16* phiP = poly ? phiB : phiA;
      uint32_t pm[4] = {0u, 0u, 0u, 0u};
#pragma unroll
      for (int mt = 0; mt < 4; ++mt) {
        if (mt < mtP) {
          const f32x4 a0 = poly ? aB[mt][0] : aA[mt][0];
          const f32x4 a1 = poly ? aB[mt][1] : aA[mt][1];
          const int row = mt * 16 + l15;
          float4 r01 = *reinterpret_cast<const float4*>(&stats_s[poly][row][0]);
          float4 r23 = *reinterpret_cast<const float4*>(&stats_s[poly][row][2]);
          float s = (r01.x + r01.z) + (r23.x + r23.z);
          float q = (r01.y + r01.w) + (r23.y + r23.w);
          float mu = s * (1.0f / 128.0f);
          float var = q * (1.0f / 128.0f) - mu * mu;
          float rs = rsqrtf(var + 1e-5f);
          // packed f16 LN-affine + relu: v = max(((a - mu) * rs) * g + be, 0)
          const uint32_t nmu = pkrtz2(-mu, -mu);
          const uint32_t rsp = pkrtz2(rs, rs);
          uint32_t ap0 = pkrtz2(a0[0], a0[1]), ap1 = pkrtz2(a0[2], a0[3]);
          uint32_t ap2 = pkrtz2(a1[0], a1[1]), ap3 = pkrtz2(a1[2], a1[3]);
          uint32_t v0 = pkmax(pkfma(pkmul(pkadd(ap0, nmu), rsp), gp0, bp0), zero);
          uint32_t v1 = pkmax(pkfma(pkmul(pkadd(ap1, nmu), rsp), gp1, bp1), zero);
          uint32_t v2 = pkmax(pkfma(pkmul(pkadd(ap2, nmu), rsp), gp2, bp2), zero);
          uint32_t v3 = pkmax(pkfma(pkmul(pkadd(ap3, nmu), rsp), gp3, bp3), zero);
          if (layer < 2) {  // x' write (b64 pairs)
            *reinterpret_cast<uint2*>(&xP[row * XSTR + cb0]) = make_uint2(v0, v1);
            *reinterpret_cast<uint2*>(&xP[row * XSTR + cb1]) = make_uint2(v2, v3);
          }
          const bool valid = row < lenP;
          pm[0] = pkmax(pm[0], valid ? v0 : zero);
          pm[1] = pkmax(pm[1], valid ? v1 : zero);
          pm[2] = pkmax(pm[2], valid ? v2 : zero);
          pm[3] = pkmax(pm[3], valid ? v3 : zero);
        }
      }
#pragma unroll
      for (int d = 1; d <= 8; d <<= 1) {
#pragma unroll
        for (int j = 0; j < 4; ++j)
          pm[j] = pkmax(pm[j], (uint32_t)__shfl_xor((int)pm[j], d));
      }

      if (layer < 2) {
        if (l15 == 0) {
          *reinterpret_cast<uint2*>(&phiP[cb0]) = make_uint2(pm[0], pm[1]);
          *reinterpret_cast<uint2*>(&phiP[cb1]) = make_uint2(pm[2], pm[3]);
        }
      } else {
        if (l15 == 0) {  // output = concat(phi3, phi3)
          PkU q0, q1, q2, q3;
          q0.u = pm[0]; q1.u = pm[1]; q2.u = pm[2]; q3.u = pm[3];
          float4 o0 = make_float4((float)q0.h[0], (float)q0.h[1], (float)q1.h[0], (float)q1.h[1]);
          float4 o1 = make_float4((float)q2.h[0], (float)q2.h[1], (float)q3.h[0], (float)q3.h[1]);
          float* op = out + (size_t)(poly ? pB : pA) * 256;
          *reinterpret_cast<float4*>(op + cb0) = o0;
          *reinterpret_cast<float4*>(op + cb1) = o1;
          *reinterpret_cast<float4*>(op + 128 + cb0) = o0;
          *reinterpret_cast<float4*>(op + 128 + cb1) = o1;
        }
      }
    }
    if (layer < 2) __syncthreads();  // x' + phi ready for next layer
  }
}

extern "C" void kernel_launch(void* const* d_in, const int* in_sizes, int n_in,
                              void* d_out, int out_size, void* d_ws, size_t ws_size,
                              hipStream_t stream) {
  const float* hs  = (const float*)d_in[0];
  const int* lens  = (const int*)d_in[1];
  const float* W1  = (const float*)d_in[2];
  const float* b1  = (const float*)d_in[3];
  const float* g1  = (const float*)d_in[4];
  const float* be1 = (const float*)d_in[5];
  const float* W2  = (const float*)d_in[6];
  const float* b2  = (const float*)d_in[7];
  const float* g2  = (const float*)d_in[8];
  const float* be2 = (const float*)d_in[9];
  const float* W3  = (const float*)d_in[10];
  const float* b3  = (const float*)d_in[11];
  const float* g3  = (const float*)d_in[12];
  const float* be3 = (const float*)d_in[13];
  float* out = (float*)d_out;
  f16* wt = (f16*)d_ws;  // needs (17408 + 2*33792)*2 = 169984 B of scratch

  const int prep_total = W1_ELEMS + 2 * W23_ELEMS;
  prep_weights<<<(prep_total + 255) / 256, 256, 0, stream>>>(W1, W2, W3, wt);
  fused_subgraph<<<PCNT / 2, 256, 0, stream>>>(hs, lens, wt,
                                               b1, g1, be1, b2, g2, be2, b3, g3, be3,
                                               out);
}

// Round 18
// 108.958 us; speedup vs baseline: 1.4342x; 1.4342x over previous
//
#include <hip/hip_runtime.h>
#include <stdint.h>

// Problem constants (fixed by the reference): P=8192, L=64, H=128.
#define PCNT 8192
#define LROW 64
#define HDIM 128
#define XSTR 136                    // x_lds k-stride (f16), 16B aligned
#define W1STR 136                   // W1^T k-stride (K=128 + 8 pad)
#define W23STR 264                  // W2^T/W3^T k-stride (K=256 + 8 pad)
#define W1_ELEMS (128 * W1STR)      // 17408
#define W23_ELEMS (128 * W23STR)    // 33792

typedef _Float16 f16;
typedef __attribute__((ext_vector_type(8))) _Float16 half8;
typedef __attribute__((ext_vector_type(2))) __fp16 fp16x2;   // builtin cvt_pkrtz type
typedef __attribute__((ext_vector_type(4))) float f32x4;

#define MFMA16(A, B, C) __builtin_amdgcn_mfma_f32_16x16x32_f16((A), (B), (C), 0, 0, 0)

__device__ __forceinline__ half8 ldh8(const f16* p) {
  return *reinterpret_cast<const half8*>(p);
}

union PkU { uint32_t u; fp16x2 h; };

// f32 pair -> packed f16 (round-toward-zero), 1 instruction
__device__ __forceinline__ uint32_t pkrtz2(float a, float b) {
  PkU r;
  r.h = __builtin_amdgcn_cvt_pkrtz(a, b);
  return r.u;
}

__device__ __forceinline__ uint32_t pkmax(uint32_t a, uint32_t b) {
  uint32_t d;
  asm("v_pk_max_f16 %0, %1, %2" : "=v"(d) : "v"(a), "v"(b));
  return d;
}
__device__ __forceinline__ uint32_t pkadd(uint32_t a, uint32_t b) {
  uint32_t d;
  asm("v_pk_add_f16 %0, %1, %2" : "=v"(d) : "v"(a), "v"(b));
  return d;
}
__device__ __forceinline__ uint32_t pkmul(uint32_t a, uint32_t b) {
  uint32_t d;
  asm("v_pk_mul_f16 %0, %1, %2" : "=v"(d) : "v"(a), "v"(b));
  return d;
}
__device__ __forceinline__ uint32_t pkfma(uint32_t a, uint32_t b, uint32_t c) {
  uint32_t d;
  asm("v_pk_fma_f16 %0, %1, %2, %3" : "=v"(d) : "v"(a), "v"(b), "v"(c));
  return d;
}

// ---------------------------------------------------------------------------
// Prep: ws = 3 transposed fp16 weight buffers (fused-K layout):
//   buf0 @0:                 W1^T  [c][k], k<128 real, stride 136
//   buf1 @W1_ELEMS:          W2^T  [c][k], k<256 real (Wa2|Wb2), stride 264
//   buf2 @W1_ELEMS+W23_ELEMS W3^T  same, stride 264
// ---------------------------------------------------------------------------
__global__ void prep_weights(const float* __restrict__ W1,
                             const float* __restrict__ W2,
                             const float* __restrict__ W3,
                             f16* __restrict__ wt) {
  int idx = blockIdx.x * 256 + threadIdx.x;
  if (idx >= W1_ELEMS + 2 * W23_ELEMS) return;
  float v = 0.0f;
  if (idx < W1_ELEMS) {
    int c = idx / W1STR, k = idx - c * W1STR;
    if (k < 128) v = W1[k * 128 + c];
  } else {
    int rem = idx - W1_ELEMS;
    const float* W = (rem < W23_ELEMS) ? W2 : W3;
    if (rem >= W23_ELEMS) rem -= W23_ELEMS;
    int c = rem / W23STR, k = rem - c * W23STR;
    if (k < 256) v = W[k * 128 + c];
  }
  wt[idx] = (f16)v;
}

// stage one polyline's rows [0,16*mtiles): fp32 -> fp16 (packed cvt),
// b128 LDS writes
__device__ __forceinline__ void stage_x(f16* __restrict__ x_lds,
                                        const float* __restrict__ hp,
                                        int mtiles, int tid) {
  for (int it = 0; it < mtiles; ++it) {
    int e = (it * 256 + tid) * 8;
    int r = e >> 7, c = e & 127;
    float4 va = *reinterpret_cast<const float4*>(hp + e);
    float4 vb = *reinterpret_cast<const float4*>(hp + e + 4);
    uint4 hv;
    hv.x = pkrtz2(va.x, va.y);
    hv.y = pkrtz2(va.z, va.w);
    hv.z = pkrtz2(vb.x, vb.y);
    hv.w = pkrtz2(vb.z, vb.w);
    *reinterpret_cast<uint4*>(&x_lds[r * XSTR + c]) = hv;
  }
}

// ---------------------------------------------------------------------------
// Fused kernel (R15 base — the proven regime): transposed-D, TWO polylines
// per block processed CONCURRENTLY (each weight fragment load feeds both
// GEMMs), bias seeds pv, packed-f16 epilogue, one stats + one phi/x' barrier
// per layer. R18 delta vs R15: the rank-1 phi term is UN-fused — computed
// once per polyline (8 MFMAs: pva = bias + phi @ Wb, row-constant D) instead
// of per-M-tile inside the K-loop (was ~40 MFMAs/layer computing 16 distinct
// results). acc is seeded with pva; main K-loop is a clean 4-iteration loop
// over x fragments only. R9-proven ordering (44 VGPR there): no new
// cross-barrier live ranges. __launch_bounds__(256,4): proven spill-free.
// ---------------------------------------------------------------------------
__global__ __launch_bounds__(256, 4)
void fused_subgraph(const float* __restrict__ hs,
                    const int* __restrict__ lens,
                    const f16* __restrict__ wt,
                    const float* __restrict__ b1, const float* __restrict__ g1, const float* __restrict__ be1,
                    const float* __restrict__ b2, const float* __restrict__ g2, const float* __restrict__ be2,
                    const float* __restrict__ b3, const float* __restrict__ g3, const float* __restrict__ be3,
                    float* __restrict__ out) {
  __shared__ __align__(16) f16 xA[LROW * XSTR];      // 17408 B
  __shared__ __align__(16) f16 xB[LROW * XSTR];      // 17408 B
  __shared__ __align__(16) float2 stats_s[2][LROW][4];  // [poly][row][wave], 4 KB
  __shared__ __align__(16) f16 phiA[HDIM];
  __shared__ __align__(16) f16 phiB[HDIM];

  const int tid = threadIdx.x;
  const int w = tid >> 6;   // wave 0..3
  const int l = tid & 63;   // lane
  const int pA = blockIdx.x * 2;
  const int pB = pA + 1;

  int lenA = lens[pA];
  lenA = (lenA < 1) ? 1 : (lenA > LROW ? LROW : lenA);
  const int mtA = (lenA + 15) >> 4;
  int lenB = lens[pB];
  lenB = (lenB < 1) ? 1 : (lenB > LROW ? LROW : lenB);
  const int mtB = (lenB + 15) >> 4;

  const int l15 = l & 15;
  const int lg = l >> 4;                    // lane group 0..3
  const int ko = lg * 8;                    // k offset within a 32-k tile
  const int cb0 = w * 32 + lg * 4;          // lane's col base, nt=0
  const int cb1 = cb0 + 16;                 // nt=1

  // ---- stage both polylines ----
  stage_x(xA, hs + (size_t)pA * (LROW * HDIM), mtA, tid);
  stage_x(xB, hs + (size_t)pB * (LROW * HDIM), mtB, tid);
  __syncthreads();

#pragma unroll
  for (int layer = 0; layer < 3; ++layer) {
    const float* gv  = (layer == 0) ? g1  : (layer == 1) ? g2  : g3;
    const float* bev = (layer == 0) ? be1 : (layer == 1) ? be2 : be3;
    const float* bv  = (layer == 0) ? b1  : (layer == 1) ? b2  : b3;
    const f16* wa = (layer == 0) ? wt
                   : (layer == 1) ? (wt + W1_ELEMS)
                                  : (wt + W1_ELEMS + W23_ELEMS);
    const int wstr = (layer == 0) ? W1STR : W23STR;
    const int wrow0 = (w * 32 + l15) * wstr;
    const int wrow1 = wrow0 + 16 * wstr;

    // ---- pv: row-constant bias + (phi @ Wb); computed ONCE per polyline ----
    f32x4 pvA0, pvA1, pvB0, pvB1;
    {
      const float4 bl0 = *reinterpret_cast<const float4*>(bv + cb0);
      const float4 bl1 = *reinterpret_cast<const float4*>(bv + cb1);
      f32x4 s0, s1;
      s0[0] = bl0.x; s0[1] = bl0.y; s0[2] = bl0.z; s0[3] = bl0.w;
      s1[0] = bl1.x; s1[1] = bl1.y; s1[2] = bl1.z; s1[3] = bl1.w;
      pvA0 = s0; pvA1 = s1; pvB0 = s0; pvB1 = s1;
    }
    if (layer > 0) {
#pragma unroll
      for (int kc = 0; kc < 4; ++kc) {
        half8 wb0 = ldh8(&wa[wrow0 + (kc + 4) * 32 + ko]);
        half8 wb1 = ldh8(&wa[wrow1 + (kc + 4) * 32 + ko]);
        half8 phfA = ldh8(&phiA[kc * 32 + ko]);  // lane-uniform -> row-const D
        half8 phfB = ldh8(&phiB[kc * 32 + ko]);
        pvA0 = MFMA16(wb0, phfA, pvA0);
        pvA1 = MFMA16(wb1, phfA, pvA1);
        pvB0 = MFMA16(wb0, phfB, pvB0);
        pvB1 = MFMA16(wb1, phfB, pvB1);
      }
    }

    // ---- GEMM both polylines: acc = pv + (x @ Wa)^T, K=128 ----
    f32x4 aA[4][2], aB[4][2];
#pragma unroll
    for (int mt = 0; mt < 4; ++mt) {
      if (mt < mtA) { aA[mt][0] = pvA0; aA[mt][1] = pvA1; }
      if (mt < mtB) { aB[mt][0] = pvB0; aB[mt][1] = pvB1; }
    }
#pragma unroll
    for (int kc = 0; kc < 4; ++kc) {
      half8 wa0 = ldh8(&wa[wrow0 + kc * 32 + ko]);   // one load, two polylines
      half8 wa1 = ldh8(&wa[wrow1 + kc * 32 + ko]);
#pragma unroll
      for (int mt = 0; mt < 4; ++mt) {
        if (mt < mtA) {
          half8 bx = ldh8(&xA[(mt * 16 + l15) * XSTR + kc * 32 + ko]);
          aA[mt][0] = MFMA16(wa0, bx, aA[mt][0]);
          aA[mt][1] = MFMA16(wa1, bx, aA[mt][1]);
        }
      }
#pragma unroll
      for (int mt = 0; mt < 4; ++mt) {
        if (mt < mtB) {
          half8 bx = ldh8(&xB[(mt * 16 + l15) * XSTR + kc * 32 + ko]);
          aB[mt][0] = MFMA16(wa0, bx, aB[mt][0]);
          aB[mt][1] = MFMA16(wa1, bx, aB[mt][1]);
        }
      }
    }

    // ---- LN stats both polylines (f32) ----
#pragma unroll
    for (int mt = 0; mt < 4; ++mt) {
      if (mt < mtA) {
        const f32x4 a0 = aA[mt][0], a1 = aA[mt][1];
        float s = ((a0[0] + a0[1]) + (a0[2] + a0[3])) + ((a1[0] + a1[1]) + (a1[2] + a1[3]));
        float q = a0[0] * a0[0];
        q = fmaf(a0[1], a0[1], q); q = fmaf(a0[2], a0[2], q); q = fmaf(a0[3], a0[3], q);
        q = fmaf(a1[0], a1[0], q); q = fmaf(a1[1], a1[1], q);
        q = fmaf(a1[2], a1[2], q); q = fmaf(a1[3], a1[3], q);
        s += __shfl_xor(s, 16); q += __shfl_xor(q, 16);
        s += __shfl_xor(s, 32); q += __shfl_xor(q, 32);
        if (l < 16) stats_s[0][mt * 16 + l15][w] = make_float2(s, q);
      }
    }
#pragma unroll
    for (int mt = 0; mt < 4; ++mt) {
      if (mt < mtB) {
        const f32x4 a0 = aB[mt][0], a1 = aB[mt][1];
        float s = ((a0[0] + a0[1]) + (a0[2] + a0[3])) + ((a1[0] + a1[1]) + (a1[2] + a1[3]));
        float q = a0[0] * a0[0];
        q = fmaf(a0[1], a0[1], q); q = fmaf(a0[2], a0[2], q); q = fmaf(a0[3], a0[3], q);
        q = fmaf(a1[0], a1[0], q); q = fmaf(a1[1], a1[1], q);
        q = fmaf(a1[2], a1[2], q); q = fmaf(a1[3], a1[3], q);
        s += __shfl_xor(s, 16); q += __shfl_xor(q, 16);
        s += __shfl_xor(s, 32); q += __shfl_xor(q, 32);
        if (l < 16) stats_s[1][mt * 16 + l15][w] = make_float2(s, q);
      }
    }
    __syncthreads();

    // ---- epilogues, packed f16 (shared g/beta packs) ----
    const float4 gg0 = *reinterpret_cast<const float4*>(gv + cb0);
    const float4 gg1 = *reinterpret_cast<const float4*>(gv + cb1);
    const float4 eb0 = *reinterpret_cast<const float4*>(bev + cb0);
    const float4 eb1 = *reinterpret_cast<const float4*>(bev + cb1);
    const uint32_t gp0 = pkrtz2(gg0.x, gg0.y), gp1 = pkrtz2(gg0.z, gg0.w);
    const uint32_t gp2 = pkrtz2(gg1.x, gg1.y), gp3 = pkrtz2(gg1.z, gg1.w);
    const uint32_t bp0 = pkrtz2(eb0.x, eb0.y), bp1 = pkrtz2(eb0.z, eb0.w);
    const uint32_t bp2 = pkrtz2(eb1.x, eb1.y), bp3 = pkrtz2(eb1.z, eb1.w);
    const uint32_t zero = 0u;

#pragma unroll
    for (int poly = 0; poly < 2; ++poly) {
      const int mtP = poly ? mtB : mtA;
      const int lenP = poly ? lenB : lenA;
      f16* xP = poly ? xB : xA;
      f16* phiP = poly ? phiB : phiA;
      uint32_t pm[4] = {0u, 0u, 0u, 0u};
#pragma unroll
      for (int mt = 0; mt < 4; ++mt) {
        if (mt < mtP) {
          const f32x4 a0 = poly ? aB[mt][0] : aA[mt][0];
          const f32x4 a1 = poly ? aB[mt][1] : aA[mt][1];
          const int row = mt * 16 + l15;
          float4 r01 = *reinterpret_cast<const float4*>(&stats_s[poly][row][0]);
          float4 r23 = *reinterpret_cast<const float4*>(&stats_s[poly][row][2]);
          float s = (r01.x + r01.z) + (r23.x + r23.z);
          float q = (r01.y + r01.w) + (r23.y + r23.w);
          float mu = s * (1.0f / 128.0f);
          float var = q * (1.0f / 128.0f) - mu * mu;
          float rs = rsqrtf(var + 1e-5f);
          // packed f16 LN-affine + relu: v = max(((a - mu) * rs) * g + be, 0)
          const uint32_t nmu = pkrtz2(-mu, -mu);
          const uint32_t rsp = pkrtz2(rs, rs);
          uint32_t ap0 = pkrtz2(a0[0], a0[1]), ap1 = pkrtz2(a0[2], a0[3]);
          uint32_t ap2 = pkrtz2(a1[0], a1[1]), ap3 = pkrtz2(a1[2], a1[3]);
          uint32_t v0 = pkmax(pkfma(pkmul(pkadd(ap0, nmu), rsp), gp0, bp0), zero);
          uint32_t v1 = pkmax(pkfma(pkmul(pkadd(ap1, nmu), rsp), gp1, bp1), zero);
          uint32_t v2 = pkmax(pkfma(pkmul(pkadd(ap2, nmu), rsp), gp2, bp2), zero);
          uint32_t v3 = pkmax(pkfma(pkmul(pkadd(ap3, nmu), rsp), gp3, bp3), zero);
          if (layer < 2) {  // x' write (b64 pairs)
            *reinterpret_cast<uint2*>(&xP[row * XSTR + cb0]) = make_uint2(v0, v1);
            *reinterpret_cast<uint2*>(&xP[row * XSTR + cb1]) = make_uint2(v2, v3);
          }
          const bool valid = row < lenP;
          pm[0] = pkmax(pm[0], valid ? v0 : zero);
          pm[1] = pkmax(pm[1], valid ? v1 : zero);
          pm[2] = pkmax(pm[2], valid ? v2 : zero);
          pm[3] = pkmax(pm[3], valid ? v3 : zero);
        }
      }
#pragma unroll
      for (int d = 1; d <= 8; d <<= 1) {
#pragma unroll
        for (int j = 0; j < 4; ++j)
          pm[j] = pkmax(pm[j], (uint32_t)__shfl_xor((int)pm[j], d));
      }

      if (layer < 2) {
        if (l15 == 0) {
          *reinterpret_cast<uint2*>(&phiP[cb0]) = make_uint2(pm[0], pm[1]);
          *reinterpret_cast<uint2*>(&phiP[cb1]) = make_uint2(pm[2], pm[3]);
        }
      } else {
        if (l15 == 0) {  // output = concat(phi3, phi3)
          PkU q0, q1, q2, q3;
          q0.u = pm[0]; q1.u = pm[1]; q2.u = pm[2]; q3.u = pm[3];
          float4 o0 = make_float4((float)q0.h[0], (float)q0.h[1], (float)q1.h[0], (float)q1.h[1]);
          float4 o1 = make_float4((float)q2.h[0], (float)q2.h[1], (float)q3.h[0], (float)q3.h[1]);
          float* op = out + (size_t)(poly ? pB : pA) * 256;
          *reinterpret_cast<float4*>(op + cb0) = o0;
          *reinterpret_cast<float4*>(op + cb1) = o1;
          *reinterpret_cast<float4*>(op + 128 + cb0) = o0;
          *reinterpret_cast<float4*>(op + 128 + cb1) = o1;
        }
      }
    }
    if (layer < 2) __syncthreads();  // x' + phi ready for next layer
  }
}

extern "C" void kernel_launch(void* const* d_in, const int* in_sizes, int n_in,
                              void* d_out, int out_size, void* d_ws, size_t ws_size,
                              hipStream_t stream) {
  const float* hs  = (const float*)d_in[0];
  const int* lens  = (const int*)d_in[1];
  const float* W1  = (const float*)d_in[2];
  const float* b1  = (const float*)d_in[3];
  const float* g1  = (const float*)d_in[4];
  const float* be1 = (const float*)d_in[5];
  const float* W2  = (const float*)d_in[6];
  const float* b2  = (const float*)d_in[7];
  const float* g2  = (const float*)d_in[8];
  const float* be2 = (const float*)d_in[9];
  const float* W3  = (const float*)d_in[10];
  const float* b3  = (const float*)d_in[11];
  const float* g3  = (const float*)d_in[12];
  const float* be3 = (const float*)d_in[13];
  float* out = (float*)d_out;
  f16* wt = (f16*)d_ws;  // needs (17408 + 2*33792)*2 = 169984 B of scratch

  const int prep_total = W1_ELEMS + 2 * W23_ELEMS;
  prep_weights<<<(prep_total + 255) / 256, 256, 0, stream>>>(W1, W2, W3, wt);
  fused_subgraph<<<PCNT / 2, 256, 0, stream>>>(hs, lens, wt,
                                               b1, g1, be1, b2, g2, be2, b3, g3, be3,
                                               out);
}